// Round 18
// baseline (533.499 us; speedup 1.0000x reference)
//
#include <hip/hip_runtime.h>
#include <cstdint>
#include <cstddef>

#define DEVI static __device__ __forceinline__

typedef unsigned short ushort_t;
typedef __attribute__((ext_vector_type(8))) short short8;
typedef __attribute__((ext_vector_type(4))) float f32x4;

DEVI float sp_softplus(float x) { return x > 20.f ? x : log1pf(__expf(x)); }
DEVI float silu_f(float x)      { return x / (1.f + __expf(-x)); }

DEVI ushort_t f2b(float v) {
    uint32_t u = __builtin_bit_cast(uint32_t, v);
    u += 0x7FFFu + ((u >> 16) & 1u);
    return (ushort_t)(u >> 16);
}
DEVI float b2f(ushort_t u) {
    uint32_t x = ((uint32_t)u) << 16;
    return __builtin_bit_cast(float, x);
}

DEVI void gload16(const ushort_t* g, ushort_t* l) {
    __builtin_amdgcn_global_load_lds(
        (const __attribute__((address_space(1))) unsigned int*)g,
        (__attribute__((address_space(3))) unsigned int*)l, 16, 0, 0);
}

#define NC 40
#define CL 25

// ---------------- LayerNorm: one wave per row of 512 ----------------
template<bool RELU, bool OUTB16>
__global__ __launch_bounds__(256) void ln_k(const float* __restrict__ x,
                                            const float* __restrict__ g,
                                            const float* __restrict__ b,
                                            void* __restrict__ yv, int M)
{
    int wid  = threadIdx.x >> 6;
    int lane = threadIdx.x & 63;
    int row  = blockIdx.x * 4 + wid;
    if (row >= M) return;
    const float* xr = x + (size_t)row * 512;
    float4 v0 = *(const float4*)(xr + lane * 8);
    float4 v1 = *(const float4*)(xr + lane * 8 + 4);
    float vals[8] = {v0.x, v0.y, v0.z, v0.w, v1.x, v1.y, v1.z, v1.w};
    float s = 0.f;
#pragma unroll
    for (int i = 0; i < 8; i++) s += vals[i];
#pragma unroll
    for (int off = 1; off < 64; off <<= 1) s += __shfl_xor(s, off);
    float mu = s * (1.f / 512.f);
    float q = 0.f;
#pragma unroll
    for (int i = 0; i < 8; i++) { float d = vals[i] - mu; q += d * d; }
#pragma unroll
    for (int off = 1; off < 64; off <<= 1) q += __shfl_xor(q, off);
    float rstd = rsqrtf(q * (1.f / 512.f) + 1e-5f);
#pragma unroll
    for (int i = 0; i < 8; i++) {
        int c = lane * 8 + i;
        float o = (vals[i] - mu) * rstd * g[c] + b[c];
        if (RELU) o = fmaxf(o, 0.f);
        if (OUTB16) ((ushort_t*)yv)[(size_t)row * 512 + c] = f2b(o);
        else        ((float*)yv)[(size_t)row * 512 + c] = o;
    }
}

// ---- fused: h = relu(LN(x)*g0+b0); lnbb = bf16(LN(h)*g1+b1). wave per row ----
__global__ __launch_bounds__(256) void ln2x_k(const float* __restrict__ x,
                                              const float* __restrict__ g0,
                                              const float* __restrict__ b0,
                                              const float* __restrict__ g1,
                                              const float* __restrict__ b1,
                                              float* __restrict__ h,
                                              ushort_t* __restrict__ lnbb, int M)
{
    int wid  = threadIdx.x >> 6;
    int lane = threadIdx.x & 63;
    int row  = blockIdx.x * 4 + wid;
    if (row >= M) return;
    const float* xr = x + (size_t)row * 512;
    float4 v0 = *(const float4*)(xr + lane * 8);
    float4 v1 = *(const float4*)(xr + lane * 8 + 4);
    float vals[8] = {v0.x, v0.y, v0.z, v0.w, v1.x, v1.y, v1.z, v1.w};
    float s = 0.f;
#pragma unroll
    for (int i = 0; i < 8; i++) s += vals[i];
#pragma unroll
    for (int off = 1; off < 64; off <<= 1) s += __shfl_xor(s, off);
    float mu = s * (1.f / 512.f);
    float q = 0.f;
#pragma unroll
    for (int i = 0; i < 8; i++) { float d = vals[i] - mu; q += d * d; }
#pragma unroll
    for (int off = 1; off < 64; off <<= 1) q += __shfl_xor(q, off);
    float rstd = rsqrtf(q * (1.f / 512.f) + 1e-5f);
    float o[8];
#pragma unroll
    for (int i = 0; i < 8; i++) {
        int c = lane * 8 + i;
        o[i] = fmaxf((vals[i] - mu) * rstd * g0[c] + b0[c], 0.f);
        h[(size_t)row * 512 + c] = o[i];
    }
    float s2 = 0.f;
#pragma unroll
    for (int i = 0; i < 8; i++) s2 += o[i];
#pragma unroll
    for (int off = 1; off < 64; off <<= 1) s2 += __shfl_xor(s2, off);
    float mu2 = s2 * (1.f / 512.f);
    float q2 = 0.f;
#pragma unroll
    for (int i = 0; i < 8; i++) { float d = o[i] - mu2; q2 += d * d; }
#pragma unroll
    for (int off = 1; off < 64; off <<= 1) q2 += __shfl_xor(q2, off);
    float rstd2 = rsqrtf(q2 * (1.f / 512.f) + 1e-5f);
#pragma unroll
    for (int i = 0; i < 8; i++) {
        int c = lane * 8 + i;
        lnbb[(size_t)row * 512 + c] = f2b((o[i] - mu2) * rstd2 * g1[c] + b1[c]);
    }
}

// ---------------- prep: conv4 w->[4][1024], dc w->[31][512], x->bf16 [2048][320] ----------------
__global__ __launch_bounds__(256) void prep_all_k(const float* __restrict__ conv_w,
                                                  const float* __restrict__ dc_w,
                                                  const float* __restrict__ x,
                                                  float* __restrict__ cwt,
                                                  float* __restrict__ dcwt,
                                                  ushort_t* __restrict__ xb)
{
    int e = blockIdx.x * 256 + threadIdx.x;
    if (e < 16384) {
        int l = e >> 12, rem = e & 4095, k = rem >> 10, d = rem & 1023;
        cwt[e] = conv_w[l * 4096 + d * 4 + k];
        return;
    }
    e -= 16384;
    if (e < 63488) {
        int l = e / 15872, rem = e % 15872, k = rem / 512, m = rem % 512;
        dcwt[e] = dc_w[l * 15872 + m * 31 + k];
        return;
    }
    e -= 63488;
    if (e < 2000 * 320) {
        int k = e % 320, row = e / 320;
        xb[e] = (k < 257) ? f2b(x[(size_t)row * 257 + k]) : (ushort_t)0;
    }
}

__global__ __launch_bounds__(256) void tr_w_k(const float* __restrict__ src,
                                              ushort_t* __restrict__ dst,
                                              int Ktrue, int N, int ldo, int srcld,
                                              size_t sstride, size_t dstride)
{
    __shared__ float tile[32][33];
    src += blockIdx.z * sstride;
    dst += blockIdx.z * dstride;
    int n0 = blockIdx.x * 32, k0 = blockIdx.y * 32;
    int tx = threadIdx.x & 31, ty = threadIdx.x >> 5;
#pragma unroll
    for (int r = 0; r < 4; r++) {
        int k = k0 + ty + r * 8, n = n0 + tx;
        tile[ty + r * 8][tx] = (k < Ktrue && n < N) ? src[(size_t)k * srcld + n] : 0.f;
    }
    __syncthreads();
#pragma unroll
    for (int r = 0; r < 4; r++) {
        int n = n0 + ty + r * 8;
        if (n < N) dst[(size_t)n * ldo + k0 + tx] = f2b(tile[tx][ty + r * 8]);
    }
}

// ---- bf16 MFMA GEMM v7 (r15) ----
template<bool BIAS, int ACT, bool RES, bool OUTF32, bool OUTB16>
__global__ __launch_bounds__(256) void gemm7(
    const ushort_t* __restrict__ A, int lda,
    const ushort_t* __restrict__ Bt, int ldb,
    const float* __restrict__ bias,
    const float* __restrict__ R, int ldr,
    float* __restrict__ C, int ldc,
    ushort_t* __restrict__ C2, int ldc2,
    int M, int N, int K,
    size_t aStr, size_t bStr, size_t cStr)
{
    __shared__ ushort_t As[3 * 4096];
    __shared__ ushort_t Bs[3 * 4096];
    A  += blockIdx.z * aStr;
    Bt += blockIdx.z * bStr;
    C  += blockIdx.z * cStr;
    C2 += blockIdx.z * cStr;

    int tid = threadIdx.x;
    int wid = tid >> 6, l = tid & 63;
    int wr = wid >> 1, wc = wid & 1;
    int lk = l >> 4, lr = l & 15;
    int rhalf = tid >> 3, oct = tid & 7;

    int nwg = gridDim.x * gridDim.y;
    int bid = blockIdx.y * gridDim.x + blockIdx.x;
    {
        int q = nwg >> 3, r = nwg & 7;
        int xcd = bid & 7, lo = bid >> 3;
        bid = (xcd < r ? xcd * (q + 1) : r * (q + 1) + (xcd - r) * q) + lo;
    }
    int bx = bid % gridDim.x, by = bid / gridDim.x;
    int bm = by * 64, bn = bx * 64;

    int cg = oct ^ (rhalf & 7);
    const ushort_t* aS0 = A  + (size_t)(bm + rhalf) * lda + cg * 8;
    const ushort_t* aS1 = aS0 + (size_t)32 * lda;
    const ushort_t* bS0 = Bt + (size_t)(bn + rhalf) * ldb + cg * 8;
    const ushort_t* bS1 = bS0 + (size_t)32 * ldb;

    int rowA = wr * 32 + lr;
    int colB = wc * 32 + lr;
    int a0 = rowA * 64 + ((0 + lk) ^ (rowA & 7)) * 8;
    int a1 = rowA * 64 + ((4 + lk) ^ (rowA & 7)) * 8;
    int b0 = colB * 64 + ((0 + lk) ^ (colB & 7)) * 8;
    int b1 = colB * 64 + ((4 + lk) ^ (colB & 7)) * 8;

    f32x4 acc00 = {0.f,0.f,0.f,0.f}, acc01 = {0.f,0.f,0.f,0.f};
    f32x4 acc10 = {0.f,0.f,0.f,0.f}, acc11 = {0.f,0.f,0.f,0.f};

#define STAGE(B_) do { \
        gload16(aS0, &As[(B_) * 4096 + tid * 8]); \
        gload16(aS1, &As[(B_) * 4096 + 2048 + tid * 8]); \
        gload16(bS0, &Bs[(B_) * 4096 + tid * 8]); \
        gload16(bS1, &Bs[(B_) * 4096 + 2048 + tid * 8]); \
        aS0 += 64; aS1 += 64; bS0 += 64; bS1 += 64; \
    } while (0)

#define COMPUTE(B_) do { \
        short8 af0 = *(const short8*)&As[(B_) * 4096 + a0]; \
        short8 af1 = *(const short8*)&As[(B_) * 4096 + 1024 + a0]; \
        short8 bf0 = *(const short8*)&Bs[(B_) * 4096 + b0]; \
        short8 bf1 = *(const short8*)&Bs[(B_) * 4096 + 1024 + b0]; \
        acc00 = __builtin_amdgcn_mfma_f32_16x16x32_bf16(af0, bf0, acc00, 0, 0, 0); \
        acc01 = __builtin_amdgcn_mfma_f32_16x16x32_bf16(af0, bf1, acc01, 0, 0, 0); \
        acc10 = __builtin_amdgcn_mfma_f32_16x16x32_bf16(af1, bf0, acc10, 0, 0, 0); \
        acc11 = __builtin_amdgcn_mfma_f32_16x16x32_bf16(af1, bf1, acc11, 0, 0, 0); \
        af0 = *(const short8*)&As[(B_) * 4096 + a1]; \
        af1 = *(const short8*)&As[(B_) * 4096 + 1024 + a1]; \
        bf0 = *(const short8*)&Bs[(B_) * 4096 + b1]; \
        bf1 = *(const short8*)&Bs[(B_) * 4096 + 1024 + b1]; \
        acc00 = __builtin_amdgcn_mfma_f32_16x16x32_bf16(af0, bf0, acc00, 0, 0, 0); \
        acc01 = __builtin_amdgcn_mfma_f32_16x16x32_bf16(af0, bf1, acc01, 0, 0, 0); \
        acc10 = __builtin_amdgcn_mfma_f32_16x16x32_bf16(af1, bf0, acc10, 0, 0, 0); \
        acc11 = __builtin_amdgcn_mfma_f32_16x16x32_bf16(af1, bf1, acc11, 0, 0, 0); \
    } while (0)

#define STEP(T_, B_) do { \
        if ((T_) + 1 < nt) asm volatile("s_waitcnt vmcnt(4)" ::: "memory"); \
        else               asm volatile("s_waitcnt vmcnt(0)" ::: "memory"); \
        __builtin_amdgcn_s_barrier(); \
        if ((T_) + 2 < nt) STAGE(((B_) + 2) % 3); \
        COMPUTE(B_); \
    } while (0)

    int nt = K >> 6;
    STAGE(0);
    if (nt > 1) STAGE(1);
    int t = 0;
    for (; t + 3 <= nt; t += 3) { STEP(t, 0); STEP(t + 1, 1); STEP(t + 2, 2); }
    if (t < nt) { STEP(t, 0); t++; }
    if (t < nt) { STEP(t, 1); }

#undef STAGE
#undef COMPUTE
#undef STEP

    f32x4 accs[2][2] = {{acc00, acc01}, {acc10, acc11}};
#pragma unroll
    for (int m = 0; m < 2; m++) {
#pragma unroll
        for (int n = 0; n < 2; n++) {
            int gn = bn + wc * 32 + n * 16 + lr;
            if (gn >= N) continue;
#pragma unroll
            for (int r = 0; r < 4; r++) {
                int gm = bm + wr * 32 + m * 16 + lk * 4 + r;
                if (gm >= M) continue;
                float v = accs[m][n][r];
                if (BIAS) v += bias[gn];
                if (ACT == 1) v = sp_softplus(v);
                if (RES) v += R[(size_t)gm * ldr + gn];
                if (OUTF32) C[(size_t)gm * ldc + gn] = v;
                if (OUTB16) C2[(size_t)gm * ldc2 + gn] = f2b(v);
            }
        }
    }
}

// ---- fused mid-section: conv4+SiLU -> xin; proj = xin@W_x; dt = softplus(proj@W_dt+b)
// one row per block (2000 blocks). wxt bf16 [64][1024]; W_dt f32 [32][1024].
__global__ __launch_bounds__(256) void midfuse_k(
    const ushort_t* __restrict__ xzb, const float* __restrict__ cwt,
    const float* __restrict__ conv_b, const ushort_t* __restrict__ wxt,
    const float* __restrict__ W_dt, const float* __restrict__ b_dt,
    ushort_t* __restrict__ xinb, float* __restrict__ proj,
    ushort_t* __restrict__ dtbb)
{
    __shared__ float s_xin[1024];
    __shared__ float s_proj[64];
    int row = blockIdx.x;
    int b = row >= 1000 ? 1 : 0;
    int t = row - b * 1000;
    int tid = threadIdx.x;
    int dg = tid * 4;

    // conv4 + silu over 4 channels
    float4 cb = *(const float4*)&conv_b[dg];
    float acc[4] = {cb.x, cb.y, cb.z, cb.w};
#pragma unroll
    for (int k = 0; k < 4; k++) {
        int tt = t - 3 + k;
        if (tt < 0) continue;
        uint2 v = *(const uint2*)&xzb[(size_t)(b * 1000 + tt) * 2048 + dg];
        float4 w = *(const float4*)&cwt[k * 1024 + dg];
        acc[0] += b2f((ushort_t)(v.x & 0xffff)) * w.x;
        acc[1] += b2f((ushort_t)(v.x >> 16))    * w.y;
        acc[2] += b2f((ushort_t)(v.y & 0xffff)) * w.z;
        acc[3] += b2f((ushort_t)(v.y >> 16))    * w.w;
    }
    uint32_t ou[4];
#pragma unroll
    for (int j = 0; j < 4; j++) {
        ou[j] = f2b(silu_f(acc[j]));
        s_xin[dg + j] = b2f((ushort_t)ou[j]);
    }
    uint2 xw = {ou[0] | (ou[1] << 16), ou[2] | (ou[3] << 16)};
    *(uint2*)&xinb[(size_t)row * 1024 + dg] = xw;
    __syncthreads();

    // proj[j] = sum_d s_xin[d] * wxt[j][d] ; quad (j = tid>>2, sub = tid&3)
    int j = tid >> 2, sub = tid & 3;
    const ushort_t* wrow = wxt + (size_t)j * 1024 + sub * 256;
    const float* xrow = s_xin + sub * 256;
    float p = 0.f;
#pragma unroll 4
    for (int i = 0; i < 256; i += 8) {
        short8 w = *(const short8*)&wrow[i];
#pragma unroll
        for (int e = 0; e < 8; e++) p += xrow[i + e] * b2f((ushort_t)w[e]);
    }
    p += __shfl_xor(p, 1);
    p += __shfl_xor(p, 2);
    if (sub == 0) {
        s_proj[j] = p;
        proj[(size_t)row * 64 + j] = p;
    }
    __syncthreads();

    // dt[j2] = softplus(b + sum_k s_proj[k] * W_dt[k][j2]) ; 4 outputs/thread
    float4 bd = *(const float4*)&b_dt[dg];
    float da[4] = {bd.x, bd.y, bd.z, bd.w};
#pragma unroll 8
    for (int k = 0; k < 32; k++) {
        float pk = s_proj[k];
        float4 w = *(const float4*)&W_dt[k * 1024 + dg];
        da[0] += pk * w.x; da[1] += pk * w.y; da[2] += pk * w.z; da[3] += pk * w.w;
    }
    uint32_t du[4];
#pragma unroll
    for (int q = 0; q < 4; q++) du[q] = f2b(sp_softplus(da[q]));
    uint2 dw = {du[0] | (du[1] << 16), du[2] | (du[3] << 16)};
    *(uint2*)&dtbb[(size_t)row * 1024 + dg] = dw;
}

// ---------------- chunked selective scan: 64 ch x 4 state-groups / block (r15) ----------------
__global__ __launch_bounds__(256) void scan_part1(const ushort_t* __restrict__ dt,
                                                  const ushort_t* __restrict__ xin,
                                                  const float* __restrict__ proj,
                                                  const float* __restrict__ A_log,
                                                  float* __restrict__ hloc,
                                                  float* __restrict__ sc)
{
    __shared__ ushort_t s_dt[CL][64], s_x[CL][64];
    __shared__ float s_B[CL][16];
    int d0 = blockIdx.x * 64;
    int c  = blockIdx.y;
    int b  = blockIdx.z;
    int tid = threadIdx.x;
    int ch = tid >> 2, st4 = tid & 3;
    int d = d0 + ch;
    int base = b * 1000 + c * CL;
    for (int lin = tid; lin < CL * 8; lin += 256) {
        int r = lin >> 3, q = lin & 7;
        size_t row = (size_t)(base + r);
        *(short8*)&s_dt[r][q * 8] = *(const short8*)&dt[row * 1024 + d0 + q * 8];
        *(short8*)&s_x[r][q * 8]  = *(const short8*)&xin[row * 1024 + d0 + q * 8];
    }
    for (int lin = tid; lin < CL * 16; lin += 256) {
        int r = lin >> 4, j = lin & 15;
        s_B[r][j] = proj[(size_t)(base + r) * 64 + 32 + j];
    }
    float4 alog = *(const float4*)&A_log[d * 16 + st4 * 4];
    float a_s[4] = {-__expf(alog.x), -__expf(alog.y), -__expf(alog.z), -__expf(alog.w)};
    __syncthreads();
    float h[4] = {0.f, 0.f, 0.f, 0.f};
    float sdt = 0.f;
#pragma unroll 5
    for (int t = 0; t < CL; t++) {
        float dtv = b2f(s_dt[t][ch]);
        float xv  = b2f(s_x[t][ch]);
        float4 Bv = *(const float4*)&s_B[t][st4 * 4];
        float dx = dtv * xv;
        sdt += dtv;
        h[0] = __expf(dtv * a_s[0]) * h[0] + dx * Bv.x;
        h[1] = __expf(dtv * a_s[1]) * h[1] + dx * Bv.y;
        h[2] = __expf(dtv * a_s[2]) * h[2] + dx * Bv.z;
        h[3] = __expf(dtv * a_s[3]) * h[3] + dx * Bv.w;
    }
    *(float4*)&hloc[((size_t)(b * NC + c) << 14) + ((size_t)d << 4) + st4 * 4] =
        (float4){h[0], h[1], h[2], h[3]};
    if (st4 == 0) sc[(b * NC + c) * 1024 + d] = sdt;
}

__global__ __launch_bounds__(256) void scan_combine(const float* __restrict__ A_log,
                                                    float* __restrict__ hloc,
                                                    const float* __restrict__ sc)
{
    int e = blockIdx.x * 256 + threadIdx.x;
    if (e >= 2 * 16384) return;
    int b = e >> 14;
    int rem = e & 16383;
    int dd = rem >> 4;
    float a_s = -__expf(A_log[rem]);
    float H = hloc[((size_t)(b * NC) << 14) + rem];
    for (int c = 1; c < NC; c++) {
        size_t idx = ((size_t)(b * NC + c) << 14) + rem;
        H = hloc[idx] + __expf(a_s * sc[(b * NC + c) * 1024 + dd]) * H;
        hloc[idx] = H;
    }
}

__global__ __launch_bounds__(256) void scan_part2(const ushort_t* __restrict__ dt,
                                                  const ushort_t* __restrict__ xin,
                                                  const float* __restrict__ proj,
                                                  const float* __restrict__ A_log,
                                                  const float* __restrict__ hend,
                                                  const float* __restrict__ Dp,
                                                  const ushort_t* __restrict__ xzb,
                                                  ushort_t* __restrict__ ysb)
{
    __shared__ ushort_t s_dt[CL][64], s_x[CL][64], s_y[CL][64];
    __shared__ float s_B[CL][16], s_C[CL][16];
    __shared__ float s_Dp[64];
    int d0 = blockIdx.x * 64;
    int c  = blockIdx.y;
    int b  = blockIdx.z;
    int tid = threadIdx.x;
    int ch = tid >> 2, st4 = tid & 3;
    int d = d0 + ch;
    int base = b * 1000 + c * CL;
    if (tid < 64) s_Dp[tid] = Dp[d0 + tid];
    for (int lin = tid; lin < CL * 8; lin += 256) {
        int r = lin >> 3, q = lin & 7;
        size_t row = (size_t)(base + r);
        *(short8*)&s_dt[r][q * 8] = *(const short8*)&dt[row * 1024 + d0 + q * 8];
        *(short8*)&s_x[r][q * 8]  = *(const short8*)&xin[row * 1024 + d0 + q * 8];
    }
    for (int lin = tid; lin < CL * 16; lin += 256) {
        int r = lin >> 4, j = lin & 15;
        s_B[r][j] = proj[(size_t)(base + r) * 64 + 32 + j];
        s_C[r][j] = proj[(size_t)(base + r) * 64 + 48 + j];
    }
    float4 alog = *(const float4*)&A_log[d * 16 + st4 * 4];
    float a_s[4] = {-__expf(alog.x), -__expf(alog.y), -__expf(alog.z), -__expf(alog.w)};
    float h[4] = {0.f, 0.f, 0.f, 0.f};
    if (c > 0) {
        float4 hv = *(const float4*)&hend[((size_t)(b * NC + c - 1) << 14)
                                          + ((size_t)d << 4) + st4 * 4];
        h[0] = hv.x; h[1] = hv.y; h[2] = hv.z; h[3] = hv.w;
    }
    __syncthreads();
#pragma unroll 5
    for (int t = 0; t < CL; t++) {
        float dtv = b2f(s_dt[t][ch]);
        float xv  = b2f(s_x[t][ch]);
        float4 Bv = *(const float4*)&s_B[t][st4 * 4];
        float4 Cv = *(const float4*)&s_C[t][st4 * 4];
        float dx = dtv * xv;
        h[0] = __expf(dtv * a_s[0]) * h[0] + dx * Bv.x;
        h[1] = __expf(dtv * a_s[1]) * h[1] + dx * Bv.y;
        h[2] = __expf(dtv * a_s[2]) * h[2] + dx * Bv.z;
        h[3] = __expf(dtv * a_s[3]) * h[3] + dx * Bv.w;
        float p = h[0] * Cv.x + h[1] * Cv.y + h[2] * Cv.z + h[3] * Cv.w;
        p += __shfl_xor(p, 1);
        p += __shfl_xor(p, 2);
        if (st4 == 0) s_y[t][ch] = f2b(p);
    }
    __syncthreads();
    for (int lin = tid; lin < CL * 8; lin += 256) {
        int r = lin >> 3, q = lin & 7;
        size_t row = (size_t)(base + r);
        int dd = d0 + q * 8;
        short8 yv = *(const short8*)&s_y[r][q * 8];
        short8 xv = *(const short8*)&s_x[r][q * 8];
        short8 zv = *(const short8*)&xzb[row * 2048 + 1024 + dd];
        short8 ov;
#pragma unroll
        for (int j = 0; j < 8; j++) {
            float o = (b2f((ushort_t)yv[j]) + b2f((ushort_t)xv[j]) * s_Dp[q * 8 + j])
                      * silu_f(b2f((ushort_t)zv[j]));
            ov[j] = (short)f2b(o);
        }
        *(short8*)&ysb[row * 1024 + dd] = ov;
    }
}

// ---- depthwise conv31 + residual + optional fused next-layer LN (row/block) ----
template<bool FUSE_LN>
__global__ __launch_bounds__(256) void dcconv_ln_k(
    const ushort_t* __restrict__ ln, const float* __restrict__ a,
    const float* __restrict__ dcwt, const float* __restrict__ bias,
    const float* __restrict__ g, const float* __restrict__ bb,
    float* __restrict__ h, ushort_t* __restrict__ out)
{
    __shared__ float red[8];
    int row = blockIdx.x;
    int b = row >= 1000 ? 1 : 0;
    int t = row - b * 1000;
    int tid = threadIdx.x;
    int m0 = tid * 2;
    float acc0 = bias[m0], acc1 = bias[m0 + 1];
#pragma unroll
    for (int k = 0; k < 31; k++) {
        int tt = t - 15 + k;
        if (tt >= 0 && tt < 1000) {
            uint32_t v = *(const uint32_t*)&ln[(size_t)(b * 1000 + tt) * 512 + m0];
            float2 w = *(const float2*)&dcwt[k * 512 + m0];
            acc0 += b2f((ushort_t)(v & 0xffff)) * w.x;
            acc1 += b2f((ushort_t)(v >> 16)) * w.y;
        }
    }
    float2 avv = *(const float2*)&a[(size_t)row * 512 + m0];
    float v0 = avv.x + acc0, v1 = avv.y + acc1;
    *(float2*)&h[(size_t)row * 512 + m0] = (float2){v0, v1};
    if (!FUSE_LN) {
        uint32_t o = (uint32_t)f2b(v0) | ((uint32_t)f2b(v1) << 16);
        *(uint32_t*)&out[(size_t)row * 512 + m0] = o;
        return;
    }
    int wv = tid >> 6, lane = tid & 63;
    float s = v0 + v1;
#pragma unroll
    for (int off = 1; off < 64; off <<= 1) s += __shfl_xor(s, off);
    if (lane == 0) red[wv] = s;
    __syncthreads();
    float mu = (red[0] + red[1] + red[2] + red[3]) * (1.f / 512.f);
    float q = (v0 - mu) * (v0 - mu) + (v1 - mu) * (v1 - mu);
#pragma unroll
    for (int off = 1; off < 64; off <<= 1) q += __shfl_xor(q, off);
    if (lane == 0) red[4 + wv] = q;
    __syncthreads();
    float var = (red[4] + red[5] + red[6] + red[7]) * (1.f / 512.f);
    float rstd = rsqrtf(var + 1e-5f);
    uint32_t o = (uint32_t)f2b((v0 - mu) * rstd * g[m0] + bb[m0])
               | ((uint32_t)f2b((v1 - mu) * rstd * g[m0 + 1] + bb[m0 + 1]) << 16);
    *(uint32_t*)&out[(size_t)row * 512 + m0] = o;
}

// ---------------- seq_mask output ----------------
__global__ void mask_k(const int* __restrict__ lengths, float* __restrict__ out)
{
    int i = blockIdx.x * 256 + threadIdx.x;
    if (i >= 2000) return;
    out[i] = ((i % 1000) < lengths[i / 1000]) ? 1.f : 0.f;
}

extern "C" void kernel_launch(void* const* d_in, const int* in_sizes, int n_in,
                              void* d_out, int out_size, void* d_ws, size_t ws_size,
                              hipStream_t stream)
{
    const float* x       = (const float*)d_in[0];
    const int*   lengths = (const int*)  d_in[1];
    const float* w_in0   = (const float*)d_in[2];
    const float* ln_in_g = (const float*)d_in[3];
    const float* ln_in_b = (const float*)d_in[4];
    const float* ln1_g   = (const float*)d_in[5];
    const float* ln1_b   = (const float*)d_in[6];
    const float* W_inproj= (const float*)d_in[7];
    const float* conv_w  = (const float*)d_in[8];
    const float* conv_b  = (const float*)d_in[9];
    const float* W_xproj = (const float*)d_in[10];
    const float* W_dt    = (const float*)d_in[11];
    const float* b_dt    = (const float*)d_in[12];
    const float* A_log   = (const float*)d_in[13];
    const float* Dp      = (const float*)d_in[14];
    const float* W_mo    = (const float*)d_in[15];
    const float* ln2_g   = (const float*)d_in[16];
    const float* ln2_b   = (const float*)d_in[17];
    const float* dc_w    = (const float*)d_in[18];
    const float* dc_b    = (const float*)d_in[19];
    const float* w_out   = (const float*)d_in[20];
    const float* b_out   = (const float*)d_in[21];

    char* p = (char*)d_ws;
    auto alloc_f = [&](size_t n) { float* r = (float*)p; p += n * 4; return r; };
    auto alloc_b = [&](size_t n) { ushort_t* r = (ushort_t*)p; p += n * 2; return r; };

    float* h    = alloc_f(2048 * 512);
    float* lnb  = alloc_f(2048 * 512);
    float* proj = alloc_f(2048 * 64);
    float* av   = alloc_f(2048 * 512);
    float* hloc = alloc_f((size_t)2 * NC * 16384);
    float* sc   = alloc_f((size_t)2 * NC * 1024);
    float* cwt  = alloc_f(4 * 4 * 1024);
    float* dcwt = alloc_f(4 * 31 * 512);
    ushort_t* xbf   = alloc_b(2048 * 320);
    ushort_t* lnbb  = alloc_b(2048 * 512);
    ushort_t* lnc   = alloc_b(2048 * 512);
    ushort_t* xzb   = alloc_b(2048 * 2048);
    ushort_t* xinb  = alloc_b(2048 * 1024);
    ushort_t* dtbb  = alloc_b(2048 * 1024);
    ushort_t* ysb   = alloc_b(2048 * 1024);
    ushort_t* hb    = alloc_b(2048 * 512);
    ushort_t* wt_in0 = alloc_b(512 * 320);
    ushort_t* wt_in  = alloc_b((size_t)4 * 2048 * 512);
    ushort_t* wt_mo  = alloc_b((size_t)4 * 512 * 1024);
    ushort_t* wt_out = alloc_b(576 * 512);
    ushort_t* wxt    = alloc_b((size_t)4 * 64 * 1024);

    dim3 blk(256);

    // ---- weight/input prep ----
    prep_all_k<<<(16384 + 63488 + 2000 * 320 + 255) / 256, blk, 0, stream>>>(
        conv_w, dc_w, x, cwt, dcwt, xbf);
    tr_w_k<<<dim3(16, 10, 1), blk, 0, stream>>>(w_in0, wt_in0, 257, 512, 320, 512, 0, 0);
    tr_w_k<<<dim3(64, 16, 4), blk, 0, stream>>>(W_inproj, wt_in, 512, 2048, 512, 2048,
                                                (size_t)512 * 2048, (size_t)2048 * 512);
    tr_w_k<<<dim3(16, 32, 4), blk, 0, stream>>>(W_mo, wt_mo, 1024, 512, 1024, 512,
                                                (size_t)1024 * 512, (size_t)512 * 1024);
    tr_w_k<<<dim3(17, 16, 1), blk, 0, stream>>>(w_out, wt_out, 512, 514, 512, 514, 0, 0);
    tr_w_k<<<dim3(2, 32, 4),  blk, 0, stream>>>(W_xproj, wxt, 1024, 64, 1024, 64,
                                                (size_t)1024 * 64, (size_t)64 * 1024);

    // ---- input projection + fused LN_in/relu + ln1_0 ----
    gemm7<false, 0, false, true, false><<<dim3(8, 32), blk, 0, stream>>>(
        xbf, 320, wt_in0, 320, nullptr, nullptr, 0, lnb, 512, nullptr, 0,
        2000, 512, 320, 0, 0, 0);
    ln2x_k<<<500, blk, 0, stream>>>(lnb, ln_in_g, ln_in_b, ln1_g, ln1_b, h, lnbb, 2000);

    for (int i = 0; i < 4; i++) {
        const float* Al = A_log + (size_t)i * 16384;
        gemm7<false, 0, false, false, true><<<dim3(32, 32), blk, 0, stream>>>(
            lnbb, 512, wt_in + (size_t)i * 2048 * 512, 512,
            nullptr, nullptr, 0, nullptr, 0, xzb, 2048, 2000, 2048, 512, 0, 0, 0);
        midfuse_k<<<2000, blk, 0, stream>>>(
            xzb, cwt + i * 4096, conv_b + i * 1024, wxt + (size_t)i * 64 * 1024,
            W_dt + (size_t)i * 32 * 1024, b_dt + i * 1024, xinb, proj, dtbb);
        scan_part1<<<dim3(16, NC, 2), blk, 0, stream>>>(dtbb, xinb, proj, Al, hloc, sc);
        scan_combine<<<128, blk, 0, stream>>>(Al, hloc, sc);
        scan_part2<<<dim3(16, NC, 2), blk, 0, stream>>>(dtbb, xinb, proj, Al, hloc,
                                                        Dp + i * 1024, xzb, ysb);
        gemm7<false, 0, true, true, false><<<dim3(8, 32), blk, 0, stream>>>(
            ysb, 1024, wt_mo + (size_t)i * 512 * 1024, 1024,
            nullptr, h, 512, av, 512, nullptr, 0, 2000, 512, 1024, 0, 0, 0);
        ln_k<false, true><<<500, blk, 0, stream>>>(av, ln2_g + i * 512, ln2_b + i * 512,
                                                   lnc, 2000);
        if (i < 3)
            dcconv_ln_k<true><<<2000, blk, 0, stream>>>(
                lnc, av, dcwt + i * 31 * 512, dc_b + i * 512,
                ln1_g + (i + 1) * 512, ln1_b + (i + 1) * 512, h, lnbb);
        else
            dcconv_ln_k<false><<<2000, blk, 0, stream>>>(
                lnc, av, dcwt + i * 31 * 512, dc_b + i * 512,
                nullptr, nullptr, h, hb);
    }

    gemm7<true, 0, false, true, false><<<dim3(9, 32), blk, 0, stream>>>(
        hb, 512, wt_out, 512, b_out, nullptr, 0, (float*)d_out, 514, nullptr, 0,
        2000, 514, 512, 0, 0, 0);
    mask_k<<<8, blk, 0, stream>>>(lengths, (float*)d_out + 2000 * 514);
}

// Round 19
// 472.092 us; speedup vs baseline: 1.1301x; 1.1301x over previous
//
#include <hip/hip_runtime.h>
#include <cstdint>
#include <cstddef>

#define DEVI static __device__ __forceinline__

typedef unsigned short ushort_t;
typedef __attribute__((ext_vector_type(8))) short short8;
typedef __attribute__((ext_vector_type(4))) float f32x4;

DEVI float sp_softplus(float x) { return x > 20.f ? x : log1pf(__expf(x)); }
DEVI float silu_f(float x)      { return x / (1.f + __expf(-x)); }

DEVI ushort_t f2b(float v) {
    uint32_t u = __builtin_bit_cast(uint32_t, v);
    u += 0x7FFFu + ((u >> 16) & 1u);
    return (ushort_t)(u >> 16);
}
DEVI float b2f(ushort_t u) {
    uint32_t x = ((uint32_t)u) << 16;
    return __builtin_bit_cast(float, x);
}

DEVI void gload16(const ushort_t* g, ushort_t* l) {
    __builtin_amdgcn_global_load_lds(
        (const __attribute__((address_space(1))) unsigned int*)g,
        (__attribute__((address_space(3))) unsigned int*)l, 16, 0, 0);
}

#define NC 40
#define CL 25

// ---------------- LayerNorm: one wave per row of 512 ----------------
template<bool RELU, bool OUTB16>
__global__ __launch_bounds__(256) void ln_k(const float* __restrict__ x,
                                            const float* __restrict__ g,
                                            const float* __restrict__ b,
                                            void* __restrict__ yv, int M)
{
    int wid  = threadIdx.x >> 6;
    int lane = threadIdx.x & 63;
    int row  = blockIdx.x * 4 + wid;
    if (row >= M) return;
    const float* xr = x + (size_t)row * 512;
    float4 v0 = *(const float4*)(xr + lane * 8);
    float4 v1 = *(const float4*)(xr + lane * 8 + 4);
    float vals[8] = {v0.x, v0.y, v0.z, v0.w, v1.x, v1.y, v1.z, v1.w};
    float s = 0.f;
#pragma unroll
    for (int i = 0; i < 8; i++) s += vals[i];
#pragma unroll
    for (int off = 1; off < 64; off <<= 1) s += __shfl_xor(s, off);
    float mu = s * (1.f / 512.f);
    float q = 0.f;
#pragma unroll
    for (int i = 0; i < 8; i++) { float d = vals[i] - mu; q += d * d; }
#pragma unroll
    for (int off = 1; off < 64; off <<= 1) q += __shfl_xor(q, off);
    float rstd = rsqrtf(q * (1.f / 512.f) + 1e-5f);
#pragma unroll
    for (int i = 0; i < 8; i++) {
        int c = lane * 8 + i;
        float o = (vals[i] - mu) * rstd * g[c] + b[c];
        if (RELU) o = fmaxf(o, 0.f);
        if (OUTB16) ((ushort_t*)yv)[(size_t)row * 512 + c] = f2b(o);
        else        ((float*)yv)[(size_t)row * 512 + c] = o;
    }
}

// ---- fused: h = relu(LN(x)*g0+b0); lnbb = bf16(LN(h)*g1+b1). wave per row ----
__global__ __launch_bounds__(256) void ln2x_k(const float* __restrict__ x,
                                              const float* __restrict__ g0,
                                              const float* __restrict__ b0,
                                              const float* __restrict__ g1,
                                              const float* __restrict__ b1,
                                              float* __restrict__ h,
                                              ushort_t* __restrict__ lnbb, int M)
{
    int wid  = threadIdx.x >> 6;
    int lane = threadIdx.x & 63;
    int row  = blockIdx.x * 4 + wid;
    if (row >= M) return;
    const float* xr = x + (size_t)row * 512;
    float4 v0 = *(const float4*)(xr + lane * 8);
    float4 v1 = *(const float4*)(xr + lane * 8 + 4);
    float vals[8] = {v0.x, v0.y, v0.z, v0.w, v1.x, v1.y, v1.z, v1.w};
    float s = 0.f;
#pragma unroll
    for (int i = 0; i < 8; i++) s += vals[i];
#pragma unroll
    for (int off = 1; off < 64; off <<= 1) s += __shfl_xor(s, off);
    float mu = s * (1.f / 512.f);
    float q = 0.f;
#pragma unroll
    for (int i = 0; i < 8; i++) { float d = vals[i] - mu; q += d * d; }
#pragma unroll
    for (int off = 1; off < 64; off <<= 1) q += __shfl_xor(q, off);
    float rstd = rsqrtf(q * (1.f / 512.f) + 1e-5f);
    float o[8];
#pragma unroll
    for (int i = 0; i < 8; i++) {
        int c = lane * 8 + i;
        o[i] = fmaxf((vals[i] - mu) * rstd * g0[c] + b0[c], 0.f);
        h[(size_t)row * 512 + c] = o[i];
    }
    float s2 = 0.f;
#pragma unroll
    for (int i = 0; i < 8; i++) s2 += o[i];
#pragma unroll
    for (int off = 1; off < 64; off <<= 1) s2 += __shfl_xor(s2, off);
    float mu2 = s2 * (1.f / 512.f);
    float q2 = 0.f;
#pragma unroll
    for (int i = 0; i < 8; i++) { float d = o[i] - mu2; q2 += d * d; }
#pragma unroll
    for (int off = 1; off < 64; off <<= 1) q2 += __shfl_xor(q2, off);
    float rstd2 = rsqrtf(q2 * (1.f / 512.f) + 1e-5f);
#pragma unroll
    for (int i = 0; i < 8; i++) {
        int c = lane * 8 + i;
        lnbb[(size_t)row * 512 + c] = f2b((o[i] - mu2) * rstd2 * g1[c] + b1[c]);
    }
}

// ---------------- prep: conv4 w->[4][1024], dc w->[31][512], x->bf16 [2048][320] ----------------
__global__ __launch_bounds__(256) void prep_all_k(const float* __restrict__ conv_w,
                                                  const float* __restrict__ dc_w,
                                                  const float* __restrict__ x,
                                                  float* __restrict__ cwt,
                                                  float* __restrict__ dcwt,
                                                  ushort_t* __restrict__ xb)
{
    int e = blockIdx.x * 256 + threadIdx.x;
    if (e < 16384) {
        int l = e >> 12, rem = e & 4095, k = rem >> 10, d = rem & 1023;
        cwt[e] = conv_w[l * 4096 + d * 4 + k];
        return;
    }
    e -= 16384;
    if (e < 63488) {
        int l = e / 15872, rem = e % 15872, k = rem / 512, m = rem % 512;
        dcwt[e] = dc_w[l * 15872 + m * 31 + k];
        return;
    }
    e -= 63488;
    if (e < 2000 * 320) {
        int k = e % 320, row = e / 320;
        xb[e] = (k < 257) ? f2b(x[(size_t)row * 257 + k]) : (ushort_t)0;
    }
}

__global__ __launch_bounds__(256) void tr_w_k(const float* __restrict__ src,
                                              ushort_t* __restrict__ dst,
                                              int Ktrue, int N, int ldo, int srcld,
                                              size_t sstride, size_t dstride)
{
    __shared__ float tile[32][33];
    src += blockIdx.z * sstride;
    dst += blockIdx.z * dstride;
    int n0 = blockIdx.x * 32, k0 = blockIdx.y * 32;
    int tx = threadIdx.x & 31, ty = threadIdx.x >> 5;
#pragma unroll
    for (int r = 0; r < 4; r++) {
        int k = k0 + ty + r * 8, n = n0 + tx;
        tile[ty + r * 8][tx] = (k < Ktrue && n < N) ? src[(size_t)k * srcld + n] : 0.f;
    }
    __syncthreads();
#pragma unroll
    for (int r = 0; r < 4; r++) {
        int n = n0 + ty + r * 8;
        if (n < N) dst[(size_t)n * ldo + k0 + tx] = f2b(tile[tx][ty + r * 8]);
    }
}

// ---- bf16 MFMA GEMM v7: pointer-incremented staging, 3-unrolled constexpr
// buffers, counted vmcnt + raw barrier, XOR bank swizzle, bijective XCD swizzle.
// ACT: 0 none, 1 softplus(+bias), 3 xproj split (gn<32 bf16 C2; else f32 C + zero C2)
template<bool BIAS, int ACT, bool RES, bool OUTF32, bool OUTB16>
__global__ __launch_bounds__(256) void gemm7(
    const ushort_t* __restrict__ A, int lda,
    const ushort_t* __restrict__ Bt, int ldb,
    const float* __restrict__ bias,
    const float* __restrict__ R, int ldr,
    float* __restrict__ C, int ldc,
    ushort_t* __restrict__ C2, int ldc2,
    int M, int N, int K,
    size_t aStr, size_t bStr, size_t cStr)
{
    __shared__ ushort_t As[3 * 4096];
    __shared__ ushort_t Bs[3 * 4096];
    A  += blockIdx.z * aStr;
    Bt += blockIdx.z * bStr;
    C  += blockIdx.z * cStr;
    C2 += blockIdx.z * cStr;

    int tid = threadIdx.x;
    int wid = tid >> 6, l = tid & 63;
    int wr = wid >> 1, wc = wid & 1;
    int lk = l >> 4, lr = l & 15;
    int rhalf = tid >> 3, oct = tid & 7;

    int nwg = gridDim.x * gridDim.y;
    int bid = blockIdx.y * gridDim.x + blockIdx.x;
    {
        int q = nwg >> 3, r = nwg & 7;
        int xcd = bid & 7, lo = bid >> 3;
        bid = (xcd < r ? xcd * (q + 1) : r * (q + 1) + (xcd - r) * q) + lo;
    }
    int bx = bid % gridDim.x, by = bid / gridDim.x;
    int bm = by * 64, bn = bx * 64;

    int cg = oct ^ (rhalf & 7);
    const ushort_t* aS0 = A  + (size_t)(bm + rhalf) * lda + cg * 8;
    const ushort_t* aS1 = aS0 + (size_t)32 * lda;
    const ushort_t* bS0 = Bt + (size_t)(bn + rhalf) * ldb + cg * 8;
    const ushort_t* bS1 = bS0 + (size_t)32 * ldb;

    int rowA = wr * 32 + lr;
    int colB = wc * 32 + lr;
    int a0 = rowA * 64 + ((0 + lk) ^ (rowA & 7)) * 8;
    int a1 = rowA * 64 + ((4 + lk) ^ (rowA & 7)) * 8;
    int b0 = colB * 64 + ((0 + lk) ^ (colB & 7)) * 8;
    int b1 = colB * 64 + ((4 + lk) ^ (colB & 7)) * 8;

    f32x4 acc00 = {0.f,0.f,0.f,0.f}, acc01 = {0.f,0.f,0.f,0.f};
    f32x4 acc10 = {0.f,0.f,0.f,0.f}, acc11 = {0.f,0.f,0.f,0.f};

#define STAGE(B_) do { \
        gload16(aS0, &As[(B_) * 4096 + tid * 8]); \
        gload16(aS1, &As[(B_) * 4096 + 2048 + tid * 8]); \
        gload16(bS0, &Bs[(B_) * 4096 + tid * 8]); \
        gload16(bS1, &Bs[(B_) * 4096 + 2048 + tid * 8]); \
        aS0 += 64; aS1 += 64; bS0 += 64; bS1 += 64; \
    } while (0)

#define COMPUTE(B_) do { \
        short8 af0 = *(const short8*)&As[(B_) * 4096 + a0]; \
        short8 af1 = *(const short8*)&As[(B_) * 4096 + 1024 + a0]; \
        short8 bf0 = *(const short8*)&Bs[(B_) * 4096 + b0]; \
        short8 bf1 = *(const short8*)&Bs[(B_) * 4096 + 1024 + b0]; \
        acc00 = __builtin_amdgcn_mfma_f32_16x16x32_bf16(af0, bf0, acc00, 0, 0, 0); \
        acc01 = __builtin_amdgcn_mfma_f32_16x16x32_bf16(af0, bf1, acc01, 0, 0, 0); \
        acc10 = __builtin_amdgcn_mfma_f32_16x16x32_bf16(af1, bf0, acc10, 0, 0, 0); \
        acc11 = __builtin_amdgcn_mfma_f32_16x16x32_bf16(af1, bf1, acc11, 0, 0, 0); \
        af0 = *(const short8*)&As[(B_) * 4096 + a1]; \
        af1 = *(const short8*)&As[(B_) * 4096 + 1024 + a1]; \
        bf0 = *(const short8*)&Bs[(B_) * 4096 + b1]; \
        bf1 = *(const short8*)&Bs[(B_) * 4096 + 1024 + b1]; \
        acc00 = __builtin_amdgcn_mfma_f32_16x16x32_bf16(af0, bf0, acc00, 0, 0, 0); \
        acc01 = __builtin_amdgcn_mfma_f32_16x16x32_bf16(af0, bf1, acc01, 0, 0, 0); \
        acc10 = __builtin_amdgcn_mfma_f32_16x16x32_bf16(af1, bf0, acc10, 0, 0, 0); \
        acc11 = __builtin_amdgcn_mfma_f32_16x16x32_bf16(af1, bf1, acc11, 0, 0, 0); \
    } while (0)

#define STEP(T_, B_) do { \
        if ((T_) + 1 < nt) asm volatile("s_waitcnt vmcnt(4)" ::: "memory"); \
        else               asm volatile("s_waitcnt vmcnt(0)" ::: "memory"); \
        __builtin_amdgcn_s_barrier(); \
        if ((T_) + 2 < nt) STAGE(((B_) + 2) % 3); \
        COMPUTE(B_); \
    } while (0)

    int nt = K >> 6;
    STAGE(0);
    if (nt > 1) STAGE(1);
    int t = 0;
    for (; t + 3 <= nt; t += 3) { STEP(t, 0); STEP(t + 1, 1); STEP(t + 2, 2); }
    if (t < nt) { STEP(t, 0); t++; }
    if (t < nt) { STEP(t, 1); }

#undef STAGE
#undef COMPUTE
#undef STEP

    f32x4 accs[2][2] = {{acc00, acc01}, {acc10, acc11}};
#pragma unroll
    for (int m = 0; m < 2; m++) {
#pragma unroll
        for (int n = 0; n < 2; n++) {
            int gn = bn + wc * 32 + n * 16 + lr;
            if (gn >= N) continue;
#pragma unroll
            for (int r = 0; r < 4; r++) {
                int gm = bm + wr * 32 + m * 16 + lk * 4 + r;
                if (gm >= M) continue;
                float v = accs[m][n][r];
                if (ACT == 3) {
                    if (gn < 32) C2[(size_t)gm * ldc2 + gn] = f2b(v);
                    else { C[(size_t)gm * ldc + gn] = v;
                           C2[(size_t)gm * ldc2 + gn] = 0; }
                    continue;
                }
                if (BIAS) v += bias[gn];
                if (ACT == 1) v = sp_softplus(v);
                if (RES) v += R[(size_t)gm * ldr + gn];
                if (OUTF32) C[(size_t)gm * ldc + gn] = v;
                if (OUTB16) C2[(size_t)gm * ldc2 + gn] = f2b(v);
            }
        }
    }
}

// ---------------- causal depthwise conv (K=4) + SiLU, vectorized x8 ----------------
__global__ __launch_bounds__(256) void conv4_silu_k(const ushort_t* __restrict__ xzb,
                                                    const float* __restrict__ cwt,
                                                    const float* __restrict__ bias,
                                                    ushort_t* __restrict__ xinb)
{
    int e = blockIdx.x * 256 + threadIdx.x;
    if (e >= 2000 * 128) return;
    int dg = (e & 127) * 8;
    int row = e >> 7;
    int b = row >= 1000 ? 1 : 0;
    int t = row - b * 1000;
    float acc[8];
#pragma unroll
    for (int j = 0; j < 8; j++) acc[j] = bias[dg + j];
#pragma unroll
    for (int k = 0; k < 4; k++) {
        int tt = t - 3 + k;
        if (tt < 0) continue;
        short8 v = *(const short8*)&xzb[(size_t)(b * 1000 + tt) * 2048 + dg];
#pragma unroll
        for (int j = 0; j < 8; j++)
            acc[j] += b2f((ushort_t)v[j]) * cwt[k * 1024 + dg + j];
    }
    short8 o;
#pragma unroll
    for (int j = 0; j < 8; j++) o[j] = (short)f2b(silu_f(acc[j]));
    *(short8*)&xinb[(size_t)row * 1024 + dg] = o;
}

// ---------------- chunked selective scan: 64 ch x 4 state-groups / block ----------------
__global__ __launch_bounds__(256) void scan_part1(const ushort_t* __restrict__ dt,
                                                  const ushort_t* __restrict__ xin,
                                                  const float* __restrict__ proj,
                                                  const float* __restrict__ A_log,
                                                  float* __restrict__ hloc,
                                                  float* __restrict__ sc)
{
    __shared__ ushort_t s_dt[CL][64], s_x[CL][64];
    __shared__ float s_B[CL][16];
    int d0 = blockIdx.x * 64;
    int c  = blockIdx.y;
    int b  = blockIdx.z;
    int tid = threadIdx.x;
    int ch = tid >> 2, st4 = tid & 3;
    int d = d0 + ch;
    int base = b * 1000 + c * CL;
    for (int lin = tid; lin < CL * 8; lin += 256) {
        int r = lin >> 3, q = lin & 7;
        size_t row = (size_t)(base + r);
        *(short8*)&s_dt[r][q * 8] = *(const short8*)&dt[row * 1024 + d0 + q * 8];
        *(short8*)&s_x[r][q * 8]  = *(const short8*)&xin[row * 1024 + d0 + q * 8];
    }
    for (int lin = tid; lin < CL * 16; lin += 256) {
        int r = lin >> 4, j = lin & 15;
        s_B[r][j] = proj[(size_t)(base + r) * 64 + 32 + j];
    }
    float4 alog = *(const float4*)&A_log[d * 16 + st4 * 4];
    float a_s[4] = {-__expf(alog.x), -__expf(alog.y), -__expf(alog.z), -__expf(alog.w)};
    __syncthreads();
    float h[4] = {0.f, 0.f, 0.f, 0.f};
    float sdt = 0.f;
#pragma unroll 5
    for (int t = 0; t < CL; t++) {
        float dtv = b2f(s_dt[t][ch]);
        float xv  = b2f(s_x[t][ch]);
        float4 Bv = *(const float4*)&s_B[t][st4 * 4];
        float dx = dtv * xv;
        sdt += dtv;
        h[0] = __expf(dtv * a_s[0]) * h[0] + dx * Bv.x;
        h[1] = __expf(dtv * a_s[1]) * h[1] + dx * Bv.y;
        h[2] = __expf(dtv * a_s[2]) * h[2] + dx * Bv.z;
        h[3] = __expf(dtv * a_s[3]) * h[3] + dx * Bv.w;
    }
    *(float4*)&hloc[((size_t)(b * NC + c) << 14) + ((size_t)d << 4) + st4 * 4] =
        (float4){h[0], h[1], h[2], h[3]};
    if (st4 == 0) sc[(b * NC + c) * 1024 + d] = sdt;
}

__global__ __launch_bounds__(256) void scan_combine(const float* __restrict__ A_log,
                                                    float* __restrict__ hloc,
                                                    const float* __restrict__ sc)
{
    int e = blockIdx.x * 256 + threadIdx.x;
    if (e >= 2 * 16384) return;
    int b = e >> 14;
    int rem = e & 16383;
    int dd = rem >> 4;
    float a_s = -__expf(A_log[rem]);
    float H = hloc[((size_t)(b * NC) << 14) + rem];
    for (int c = 1; c < NC; c++) {
        size_t idx = ((size_t)(b * NC + c) << 14) + rem;
        H = hloc[idx] + __expf(a_s * sc[(b * NC + c) * 1024 + dd]) * H;
        hloc[idx] = H;
    }
}

__global__ __launch_bounds__(256) void scan_part2(const ushort_t* __restrict__ dt,
                                                  const ushort_t* __restrict__ xin,
                                                  const float* __restrict__ proj,
                                                  const float* __restrict__ A_log,
                                                  const float* __restrict__ hend,
                                                  const float* __restrict__ Dp,
                                                  const ushort_t* __restrict__ xzb,
                                                  ushort_t* __restrict__ ysb)
{
    __shared__ ushort_t s_dt[CL][64], s_x[CL][64], s_y[CL][64];
    __shared__ float s_B[CL][16], s_C[CL][16];
    __shared__ float s_Dp[64];
    int d0 = blockIdx.x * 64;
    int c  = blockIdx.y;
    int b  = blockIdx.z;
    int tid = threadIdx.x;
    int ch = tid >> 2, st4 = tid & 3;
    int d = d0 + ch;
    int base = b * 1000 + c * CL;
    if (tid < 64) s_Dp[tid] = Dp[d0 + tid];
    for (int lin = tid; lin < CL * 8; lin += 256) {
        int r = lin >> 3, q = lin & 7;
        size_t row = (size_t)(base + r);
        *(short8*)&s_dt[r][q * 8] = *(const short8*)&dt[row * 1024 + d0 + q * 8];
        *(short8*)&s_x[r][q * 8]  = *(const short8*)&xin[row * 1024 + d0 + q * 8];
    }
    for (int lin = tid; lin < CL * 16; lin += 256) {
        int r = lin >> 4, j = lin & 15;
        s_B[r][j] = proj[(size_t)(base + r) * 64 + 32 + j];
        s_C[r][j] = proj[(size_t)(base + r) * 64 + 48 + j];
    }
    float4 alog = *(const float4*)&A_log[d * 16 + st4 * 4];
    float a_s[4] = {-__expf(alog.x), -__expf(alog.y), -__expf(alog.z), -__expf(alog.w)};
    float h[4] = {0.f, 0.f, 0.f, 0.f};
    if (c > 0) {
        float4 hv = *(const float4*)&hend[((size_t)(b * NC + c - 1) << 14)
                                          + ((size_t)d << 4) + st4 * 4];
        h[0] = hv.x; h[1] = hv.y; h[2] = hv.z; h[3] = hv.w;
    }
    __syncthreads();
#pragma unroll 5
    for (int t = 0; t < CL; t++) {
        float dtv = b2f(s_dt[t][ch]);
        float xv  = b2f(s_x[t][ch]);
        float4 Bv = *(const float4*)&s_B[t][st4 * 4];
        float4 Cv = *(const float4*)&s_C[t][st4 * 4];
        float dx = dtv * xv;
        h[0] = __expf(dtv * a_s[0]) * h[0] + dx * Bv.x;
        h[1] = __expf(dtv * a_s[1]) * h[1] + dx * Bv.y;
        h[2] = __expf(dtv * a_s[2]) * h[2] + dx * Bv.z;
        h[3] = __expf(dtv * a_s[3]) * h[3] + dx * Bv.w;
        float p = h[0] * Cv.x + h[1] * Cv.y + h[2] * Cv.z + h[3] * Cv.w;
        p += __shfl_xor(p, 1);
        p += __shfl_xor(p, 2);
        if (st4 == 0) s_y[t][ch] = f2b(p);
    }
    __syncthreads();
    for (int lin = tid; lin < CL * 8; lin += 256) {
        int r = lin >> 3, q = lin & 7;
        size_t row = (size_t)(base + r);
        int dd = d0 + q * 8;
        short8 yv = *(const short8*)&s_y[r][q * 8];
        short8 xv = *(const short8*)&s_x[r][q * 8];
        short8 zv = *(const short8*)&xzb[row * 2048 + 1024 + dd];
        short8 ov;
#pragma unroll
        for (int j = 0; j < 8; j++) {
            float o = (b2f((ushort_t)yv[j]) + b2f((ushort_t)xv[j]) * s_Dp[q * 8 + j])
                      * silu_f(b2f((ushort_t)zv[j]));
            ov[j] = (short)f2b(o);
        }
        *(short8*)&ysb[row * 1024 + dd] = ov;
    }
}

// ---- depthwise conv31 + residual + optional fused next-layer LN (row/block) ----
template<bool FUSE_LN>
__global__ __launch_bounds__(256) void dcconv_ln_k(
    const ushort_t* __restrict__ ln, const float* __restrict__ a,
    const float* __restrict__ dcwt, const float* __restrict__ bias,
    const float* __restrict__ g, const float* __restrict__ bb,
    float* __restrict__ h, ushort_t* __restrict__ out)
{
    __shared__ float red[8];
    int row = blockIdx.x;
    int b = row >= 1000 ? 1 : 0;
    int t = row - b * 1000;
    int tid = threadIdx.x;
    int m0 = tid * 2;
    float acc0 = bias[m0], acc1 = bias[m0 + 1];
#pragma unroll
    for (int k = 0; k < 31; k++) {
        int tt = t - 15 + k;
        if (tt >= 0 && tt < 1000) {
            uint32_t v = *(const uint32_t*)&ln[(size_t)(b * 1000 + tt) * 512 + m0];
            float2 w = *(const float2*)&dcwt[k * 512 + m0];
            acc0 += b2f((ushort_t)(v & 0xffff)) * w.x;
            acc1 += b2f((ushort_t)(v >> 16)) * w.y;
        }
    }
    float2 avv = *(const float2*)&a[(size_t)row * 512 + m0];
    float v0 = avv.x + acc0, v1 = avv.y + acc1;
    *(float2*)&h[(size_t)row * 512 + m0] = (float2){v0, v1};
    if (!FUSE_LN) {
        uint32_t o = (uint32_t)f2b(v0) | ((uint32_t)f2b(v1) << 16);
        *(uint32_t*)&out[(size_t)row * 512 + m0] = o;
        return;
    }
    int wv = tid >> 6, lane = tid & 63;
    float s = v0 + v1;
#pragma unroll
    for (int off = 1; off < 64; off <<= 1) s += __shfl_xor(s, off);
    if (lane == 0) red[wv] = s;
    __syncthreads();
    float mu = (red[0] + red[1] + red[2] + red[3]) * (1.f / 512.f);
    float q = (v0 - mu) * (v0 - mu) + (v1 - mu) * (v1 - mu);
#pragma unroll
    for (int off = 1; off < 64; off <<= 1) q += __shfl_xor(q, off);
    if (lane == 0) red[4 + wv] = q;
    __syncthreads();
    float var = (red[4] + red[5] + red[6] + red[7]) * (1.f / 512.f);
    float rstd = rsqrtf(var + 1e-5f);
    uint32_t o = (uint32_t)f2b((v0 - mu) * rstd * g[m0] + bb[m0])
               | ((uint32_t)f2b((v1 - mu) * rstd * g[m0 + 1] + bb[m0 + 1]) << 16);
    *(uint32_t*)&out[(size_t)row * 512 + m0] = o;
}

// ---------------- seq_mask output ----------------
__global__ void mask_k(const int* __restrict__ lengths, float* __restrict__ out)
{
    int i = blockIdx.x * 256 + threadIdx.x;
    if (i >= 2000) return;
    out[i] = ((i % 1000) < lengths[i / 1000]) ? 1.f : 0.f;
}

extern "C" void kernel_launch(void* const* d_in, const int* in_sizes, int n_in,
                              void* d_out, int out_size, void* d_ws, size_t ws_size,
                              hipStream_t stream)
{
    const float* x       = (const float*)d_in[0];
    const int*   lengths = (const int*)  d_in[1];
    const float* w_in0   = (const float*)d_in[2];
    const float* ln_in_g = (const float*)d_in[3];
    const float* ln_in_b = (const float*)d_in[4];
    const float* ln1_g   = (const float*)d_in[5];
    const float* ln1_b   = (const float*)d_in[6];
    const float* W_inproj= (const float*)d_in[7];
    const float* conv_w  = (const float*)d_in[8];
    const float* conv_b  = (const float*)d_in[9];
    const float* W_xproj = (const float*)d_in[10];
    const float* W_dt    = (const float*)d_in[11];
    const float* b_dt    = (const float*)d_in[12];
    const float* A_log   = (const float*)d_in[13];
    const float* Dp      = (const float*)d_in[14];
    const float* W_mo    = (const float*)d_in[15];
    const float* ln2_g   = (const float*)d_in[16];
    const float* ln2_b   = (const float*)d_in[17];
    const float* dc_w    = (const float*)d_in[18];
    const float* dc_b    = (const float*)d_in[19];
    const float* w_out   = (const float*)d_in[20];
    const float* b_out   = (const float*)d_in[21];

    char* p = (char*)d_ws;
    auto alloc_f = [&](size_t n) { float* r = (float*)p; p += n * 4; return r; };
    auto alloc_b = [&](size_t n) { ushort_t* r = (ushort_t*)p; p += n * 2; return r; };

    float* h    = alloc_f(2048 * 512);
    float* lnb  = alloc_f(2048 * 512);
    float* proj = alloc_f(2048 * 64);
    float* av   = alloc_f(2048 * 512);
    float* hloc = alloc_f((size_t)2 * NC * 16384);
    float* sc   = alloc_f((size_t)2 * NC * 1024);
    float* cwt  = alloc_f(4 * 4 * 1024);
    float* dcwt = alloc_f(4 * 31 * 512);
    ushort_t* xbf   = alloc_b(2048 * 320);
    ushort_t* lnbb  = alloc_b(2048 * 512);
    ushort_t* lnc   = alloc_b(2048 * 512);
    ushort_t* xzb   = alloc_b(2048 * 2048);
    ushort_t* xinb  = alloc_b(2048 * 1024);
    ushort_t* dtbb  = alloc_b(2048 * 1024);
    ushort_t* ysb   = alloc_b(2048 * 1024);
    ushort_t* hb    = alloc_b(2048 * 512);
    ushort_t* projb = alloc_b(2048 * 64);
    ushort_t* wt_in0 = alloc_b(512 * 320);
    ushort_t* wt_in  = alloc_b((size_t)4 * 2048 * 512);
    ushort_t* wt_dt  = alloc_b((size_t)4 * 1024 * 64);
    ushort_t* wt_mo  = alloc_b((size_t)4 * 512 * 1024);
    ushort_t* wt_out = alloc_b(576 * 512);
    ushort_t* wxt    = alloc_b((size_t)4 * 64 * 1024);

    dim3 blk(256);

    // ---- weight/input prep ----
    prep_all_k<<<(16384 + 63488 + 2000 * 320 + 255) / 256, blk, 0, stream>>>(
        conv_w, dc_w, x, cwt, dcwt, xbf);
    tr_w_k<<<dim3(16, 10, 1), blk, 0, stream>>>(w_in0, wt_in0, 257, 512, 320, 512, 0, 0);
    tr_w_k<<<dim3(64, 16, 4), blk, 0, stream>>>(W_inproj, wt_in, 512, 2048, 512, 2048,
                                                (size_t)512 * 2048, (size_t)2048 * 512);
    tr_w_k<<<dim3(32, 2, 4),  blk, 0, stream>>>(W_dt, wt_dt, 32, 1024, 64, 1024,
                                                (size_t)32 * 1024, (size_t)1024 * 64);
    tr_w_k<<<dim3(16, 32, 4), blk, 0, stream>>>(W_mo, wt_mo, 1024, 512, 1024, 512,
                                                (size_t)1024 * 512, (size_t)512 * 1024);
    tr_w_k<<<dim3(17, 16, 1), blk, 0, stream>>>(w_out, wt_out, 512, 514, 512, 514, 0, 0);
    tr_w_k<<<dim3(2, 32, 4),  blk, 0, stream>>>(W_xproj, wxt, 1024, 64, 1024, 64,
                                                (size_t)1024 * 64, (size_t)64 * 1024);

    // ---- input projection + fused LN_in/relu + ln1_0 ----
    gemm7<false, 0, false, true, false><<<dim3(8, 32), blk, 0, stream>>>(
        xbf, 320, wt_in0, 320, nullptr, nullptr, 0, lnb, 512, nullptr, 0,
        2000, 512, 320, 0, 0, 0);
    ln2x_k<<<500, blk, 0, stream>>>(lnb, ln_in_g, ln_in_b, ln1_g, ln1_b, h, lnbb, 2000);

    for (int i = 0; i < 4; i++) {
        const float* Al = A_log + (size_t)i * 16384;
        gemm7<false, 0, false, false, true><<<dim3(32, 32), blk, 0, stream>>>(
            lnbb, 512, wt_in + (size_t)i * 2048 * 512, 512,
            nullptr, nullptr, 0, nullptr, 0, xzb, 2048, 2000, 2048, 512, 0, 0, 0);
        conv4_silu_k<<<1000, blk, 0, stream>>>(xzb, cwt + i * 4096,
                                               conv_b + i * 1024, xinb);
        gemm7<false, 3, false, false, false><<<dim3(1, 32), blk, 0, stream>>>(
            xinb, 1024, wxt + (size_t)i * 64 * 1024, 1024,
            nullptr, nullptr, 0, proj, 64, projb, 64, 2000, 64, 1024, 0, 0, 0);
        gemm7<true, 1, false, false, true><<<dim3(16, 32), blk, 0, stream>>>(
            projb, 64, wt_dt + (size_t)i * 1024 * 64, 64,
            b_dt + i * 1024, nullptr, 0, nullptr, 0, dtbb, 1024,
            2000, 1024, 64, 0, 0, 0);
        scan_part1<<<dim3(16, NC, 2), blk, 0, stream>>>(dtbb, xinb, proj, Al, hloc, sc);
        scan_combine<<<128, blk, 0, stream>>>(Al, hloc, sc);
        scan_part2<<<dim3(16, NC, 2), blk, 0, stream>>>(dtbb, xinb, proj, Al, hloc,
                                                        Dp + i * 1024, xzb, ysb);
        gemm7<false, 0, true, true, false><<<dim3(8, 32), blk, 0, stream>>>(
            ysb, 1024, wt_mo + (size_t)i * 512 * 1024, 1024,
            nullptr, h, 512, av, 512, nullptr, 0, 2000, 512, 1024, 0, 0, 0);
        ln_k<false, true><<<500, blk, 0, stream>>>(av, ln2_g + i * 512, ln2_b + i * 512,
                                                   lnc, 2000);
        if (i < 3)
            dcconv_ln_k<true><<<2000, blk, 0, stream>>>(
                lnc, av, dcwt + i * 31 * 512, dc_b + i * 512,
                ln1_g + (i + 1) * 512, ln1_b + (i + 1) * 512, h, lnbb);
        else
            dcconv_ln_k<false><<<2000, blk, 0, stream>>>(
                lnc, av, dcwt + i * 31 * 512, dc_b + i * 512,
                nullptr, nullptr, h, hb);
    }

    gemm7<true, 0, false, true, false><<<dim3(9, 32), blk, 0, stream>>>(
        hb, 512, wt_out, 512, b_out, nullptr, 0, (float*)d_out, 514, nullptr, 0,
        2000, 514, 512, 0, 0, 0);
    mask_k<<<8, blk, 0, stream>>>(lengths, (float*)d_out + 2000 * 514);
}